// Round 1
// baseline (203.948 us; speedup 1.0000x reference)
//
#include <hip/hip_runtime.h>

// Problem constants (from reference setup_inputs)
constexpr int Bsz   = 1024;     // batch
constexpr int F0    = 20000;    // input features
constexpr int NOUT0 = 5000, NOUT1 = 1000, NOUT2 = 256;
constexpr int NE0   = 100000, NE1 = 50000, NE2 = 10000;
constexpr int CNT_N  = NOUT0 + NOUT1 + NOUT2;   // 6256
constexpr int OFFS_N = CNT_N + 3;               // 6259
constexpr int CSR_N  = NE0 + NE1 + NE2;         // 160000

// ---------------------------------------------------------------------------
// Transpose data (B, F0) -> dataT (F0, B), fused with *p0 row scale.
// Tiled 32x32 via LDS, block (32,8).
__global__ __launch_bounds__(256) void transpose_scale(
    const float* __restrict__ data, const float* __restrict__ p0,
    float* __restrict__ dataT)
{
    __shared__ float tile[32][33];
    const int tx = threadIdx.x, ty = threadIdx.y;
    const int c0 = blockIdx.x * 32;   // F0 dim
    const int r0 = blockIdx.y * 32;   // B dim
#pragma unroll
    for (int i = ty; i < 32; i += 8)
        tile[i][tx] = data[(size_t)(r0 + i) * F0 + (c0 + tx)];
    __syncthreads();
#pragma unroll
    for (int i = ty; i < 32; i += 8) {
        const int r = c0 + i;  // F0 index
        dataT[(size_t)r * Bsz + (r0 + tx)] = tile[tx][i] * p0[r];
    }
}

// ---------------------------------------------------------------------------
// CSR build: count, scan, scatter (all 3 layers at once)
__global__ __launch_bounds__(256) void count_edges(
    const int* __restrict__ dst0, const int* __restrict__ dst1,
    const int* __restrict__ dst2, int* __restrict__ cnt)
{
    const int i = blockIdx.x * 256 + threadIdx.x;
    if (i < NE0)                 atomicAdd(&cnt[dst0[i]], 1);
    else if (i < NE0 + NE1)      atomicAdd(&cnt[NOUT0 + dst1[i - NE0]], 1);
    else if (i < NE0 + NE1 + NE2) atomicAdd(&cnt[NOUT0 + NOUT1 + dst2[i - NE0 - NE1]], 1);
}

__global__ __launch_bounds__(1024) void scan_offs(
    const int* __restrict__ cnt, int* __restrict__ offs, int* __restrict__ cursor)
{
    const int L = blockIdx.x;
    const int nout  = (L == 0) ? NOUT0 : (L == 1) ? NOUT1 : NOUT2;
    const int cbase = (L == 0) ? 0 : (L == 1) ? NOUT0 : NOUT0 + NOUT1;
    const int obase = (L == 0) ? 0 : (L == 1) ? NOUT0 + 1 : NOUT0 + NOUT1 + 2;
    const int* c  = cnt + cbase;
    int* ofs      = offs + obase;
    int* cur      = cursor + cbase;

    __shared__ int lds[1024];
    const int t = threadIdx.x;
    constexpr int CHUNK = 5;              // covers nout <= 5120
    const int base = t * CHUNK;
    int vals[CHUNK];
    int local = 0;
#pragma unroll
    for (int k = 0; k < CHUNK; ++k) {
        const int i = base + k;
        const int v = (i < nout) ? c[i] : 0;
        vals[k] = v;
        local += v;
    }
    lds[t] = local;
    __syncthreads();
    for (int d = 1; d < 1024; d <<= 1) {
        const int v = (t >= d) ? lds[t - d] : 0;
        __syncthreads();
        lds[t] += v;
        __syncthreads();
    }
    int excl = lds[t] - local;
#pragma unroll
    for (int k = 0; k < CHUNK; ++k) {
        const int i = base + k;
        if (i < nout) { ofs[i] = excl; cur[i] = excl; }
        excl += vals[k];
    }
    if (t == 1023) ofs[nout] = lds[1023];
}

__global__ __launch_bounds__(256) void scatter_edges(
    const int* __restrict__ src0, const int* __restrict__ dst0,
    const int* __restrict__ src1, const int* __restrict__ dst1,
    const int* __restrict__ src2, const int* __restrict__ dst2,
    int* __restrict__ cursor, int* __restrict__ csr)
{
    const int i = blockIdx.x * 256 + threadIdx.x;
    if (i < NE0) {
        const int pos = atomicAdd(&cursor[dst0[i]], 1);
        csr[pos] = src0[i];
    } else if (i < NE0 + NE1) {
        const int k = i - NE0;
        const int pos = atomicAdd(&cursor[NOUT0 + dst1[k]], 1);
        csr[NE0 + pos] = src1[k];
    } else if (i < NE0 + NE1 + NE2) {
        const int k = i - NE0 - NE1;
        const int pos = atomicAdd(&cursor[NOUT0 + NOUT1 + dst2[k]], 1);
        csr[NE0 + NE1 + pos] = src2[k];
    }
}

// ---------------------------------------------------------------------------
// One layer: block j sums rows xT[csr[e]] over its bucket, mean+relu, scaled
// by pnext (the NEXT layer's p, fused), written transposed.
// 256 threads x float4 = 1024 floats = full batch row.
__global__ __launch_bounds__(256) void layer_fwd(
    const float4* __restrict__ xT, const int* __restrict__ csr,
    const int* __restrict__ offs, const float* __restrict__ pnext,
    float4* __restrict__ yT)
{
    const int j = blockIdx.x;
    const int t = threadIdx.x;
    const int beg = offs[j], end = offs[j + 1];

    float4 acc = make_float4(0.f, 0.f, 0.f, 0.f);
    int e = beg;
    int sn = (e < end) ? csr[e] : 0;
    while (e < end) {
        const int s = sn;
        ++e;
        if (e < end) sn = csr[e];   // prefetch next src index
        const float4 v = xT[(size_t)s * (Bsz / 4) + t];
        acc.x += v.x; acc.y += v.y; acc.z += v.z; acc.w += v.w;
    }
    const float inv = 1.0f / fmaxf((float)(end - beg), 1.0f);
    const float sc = pnext ? pnext[j] : 1.0f;
    float4 r;
    r.x = fmaxf(acc.x * inv, 0.f) * sc;
    r.y = fmaxf(acc.y * inv, 0.f) * sc;
    r.z = fmaxf(acc.z * inv, 0.f) * sc;
    r.w = fmaxf(acc.w * inv, 0.f) * sc;
    yT[(size_t)j * (Bsz / 4) + t] = r;
}

// ---------------------------------------------------------------------------
// Head: out (B,10) = y2 (B,256) @ W.T (256,10) + b, with y2 stored transposed.
__global__ __launch_bounds__(256) void head_gemm(
    const float* __restrict__ y2T, const float* __restrict__ W,
    const float* __restrict__ bias, float* __restrict__ out)
{
    __shared__ float ws[10 * 256];
    __shared__ float bs[10];
    const int t = threadIdx.x;
    for (int i = t; i < 10 * 256; i += 256) ws[i] = W[i];
    if (t < 10) bs[t] = bias[t];
    __syncthreads();

    const int b = blockIdx.x * 256 + t;
    float acc[10];
#pragma unroll
    for (int o = 0; o < 10; ++o) acc[o] = bs[o];
    for (int k = 0; k < 256; ++k) {
        const float v = y2T[(size_t)k * Bsz + b];
#pragma unroll
        for (int o = 0; o < 10; ++o) acc[o] += v * ws[o * 256 + k];
    }
#pragma unroll
    for (int o = 0; o < 10; ++o) out[(size_t)b * 10 + o] = acc[o];
}

// ---------------------------------------------------------------------------
extern "C" void kernel_launch(void* const* d_in, const int* in_sizes, int n_in,
                              void* d_out, int out_size, void* d_ws, size_t ws_size,
                              hipStream_t stream)
{
    const float* data = (const float*)d_in[0];
    const float* p0   = (const float*)d_in[1];
    const float* p1   = (const float*)d_in[2];
    const float* p2   = (const float*)d_in[3];
    const float* W    = (const float*)d_in[4];
    const float* bias = (const float*)d_in[5];
    const int* src0 = (const int*)d_in[6];
    const int* dst0 = (const int*)d_in[7];
    const int* src1 = (const int*)d_in[8];
    const int* dst1 = (const int*)d_in[9];
    const int* src2 = (const int*)d_in[10];
    const int* dst2 = (const int*)d_in[11];

    char* ws = (char*)d_ws;
    auto align = [](size_t x) { return (x + 255) & ~size_t(255); };
    size_t o = 0;
    float* dataT = (float*)(ws + o); o = align(o + (size_t)F0 * Bsz * 4);
    float* y0    = (float*)(ws + o); o = align(o + (size_t)NOUT0 * Bsz * 4);
    float* y1    = (float*)(ws + o); o = align(o + (size_t)NOUT1 * Bsz * 4);
    float* y2    = (float*)(ws + o); o = align(o + (size_t)NOUT2 * Bsz * 4);
    int* cnt     = (int*)(ws + o);   o = align(o + (size_t)CNT_N * 4);
    int* offs    = (int*)(ws + o);   o = align(o + (size_t)OFFS_N * 4);
    int* cursor  = (int*)(ws + o);   o = align(o + (size_t)CNT_N * 4);
    int* csr     = (int*)(ws + o);   o = align(o + (size_t)CSR_N * 4);

    hipMemsetAsync(cnt, 0, (size_t)CNT_N * 4, stream);

    constexpr int totE = NE0 + NE1 + NE2;
    count_edges<<<(totE + 255) / 256, 256, 0, stream>>>(dst0, dst1, dst2, cnt);
    scan_offs<<<3, 1024, 0, stream>>>(cnt, offs, cursor);
    scatter_edges<<<(totE + 255) / 256, 256, 0, stream>>>(
        src0, dst0, src1, dst1, src2, dst2, cursor, csr);

    transpose_scale<<<dim3(F0 / 32, Bsz / 32), dim3(32, 8), 0, stream>>>(data, p0, dataT);

    layer_fwd<<<NOUT0, 256, 0, stream>>>((const float4*)dataT, csr, offs, p1, (float4*)y0);
    layer_fwd<<<NOUT1, 256, 0, stream>>>((const float4*)y0, csr + NE0, offs + NOUT0 + 1, p2, (float4*)y1);
    layer_fwd<<<NOUT2, 256, 0, stream>>>((const float4*)y1, csr + NE0 + NE1, offs + NOUT0 + NOUT1 + 2,
                                          nullptr, (float4*)y2);

    head_gemm<<<Bsz / 256, 256, 0, stream>>>(y2, W, bias, (float*)d_out);
}

// Round 2
// 189.095 us; speedup vs baseline: 1.0785x; 1.0785x over previous
//
#include <hip/hip_runtime.h>

// Problem constants (from reference setup_inputs)
constexpr int Bsz   = 1024;     // batch
constexpr int F0    = 20000;    // input features
constexpr int NOUT0 = 5000, NOUT1 = 1000, NOUT2 = 256;
constexpr int NE0   = 100000, NE1 = 50000, NE2 = 10000;
constexpr int CNT_N  = NOUT0 + NOUT1 + NOUT2;   // 6256
constexpr int OFFS_N = CNT_N + 3;               // 6259
constexpr int CSR_N  = NE0 + NE1 + NE2;         // 160000

// ---------------------------------------------------------------------------
// Transpose data (B, F0) -> dataT (F0, B), fused with *p0 row scale.
// 64x64 tile, float4 on both global sides (16B/lane). F-edge guarded
// (F0 % 64 != 0). LDS scalar with +1 pad (2-way bank alias = free).
__global__ __launch_bounds__(256) void transpose_scale(
    const float* __restrict__ data, const float* __restrict__ p0,
    float* __restrict__ dataT)
{
    __shared__ float tile[64][65];
    const int t  = threadIdx.x;
    const int c0 = blockIdx.x * 64;   // F0 dim
    const int r0 = blockIdx.y * 64;   // B dim

    const int f4 = t & 15;            // float4 column group within tile
    const int rr = t >> 4;            // 0..15
    const int col = c0 + f4 * 4;
    if (col < F0) {                   // F0 % 4 == 0, so f4-granular guard is exact
#pragma unroll
        for (int p = 0; p < 4; ++p) {
            const int br = rr + p * 16;
            const float4 v = *(const float4*)&data[(size_t)(r0 + br) * F0 + col];
            tile[br][f4 * 4 + 0] = v.x;
            tile[br][f4 * 4 + 1] = v.y;
            tile[br][f4 * 4 + 2] = v.z;
            tile[br][f4 * 4 + 3] = v.w;
        }
    }
    __syncthreads();

    const int b4 = t & 15;            // float4 group in B dim
    const int fr = t >> 4;            // 0..15
#pragma unroll
    for (int p = 0; p < 4; ++p) {
        const int f = c0 + fr + p * 16;
        if (f < F0) {
            const float s = p0[f];
            float4 v;
            v.x = tile[b4 * 4 + 0][fr + p * 16] * s;
            v.y = tile[b4 * 4 + 1][fr + p * 16] * s;
            v.z = tile[b4 * 4 + 2][fr + p * 16] * s;
            v.w = tile[b4 * 4 + 3][fr + p * 16] * s;
            *(float4*)&dataT[(size_t)f * Bsz + r0 + b4 * 4] = v;
        }
    }
}

// ---------------------------------------------------------------------------
// CSR build: count, scan, scatter (all 3 layers at once)
__global__ __launch_bounds__(256) void count_edges(
    const int* __restrict__ dst0, const int* __restrict__ dst1,
    const int* __restrict__ dst2, int* __restrict__ cnt)
{
    const int i = blockIdx.x * 256 + threadIdx.x;
    if (i < NE0)                 atomicAdd(&cnt[dst0[i]], 1);
    else if (i < NE0 + NE1)      atomicAdd(&cnt[NOUT0 + dst1[i - NE0]], 1);
    else if (i < NE0 + NE1 + NE2) atomicAdd(&cnt[NOUT0 + NOUT1 + dst2[i - NE0 - NE1]], 1);
}

__global__ __launch_bounds__(1024) void scan_offs(
    const int* __restrict__ cnt, int* __restrict__ offs, int* __restrict__ cursor)
{
    const int L = blockIdx.x;
    const int nout  = (L == 0) ? NOUT0 : (L == 1) ? NOUT1 : NOUT2;
    const int cbase = (L == 0) ? 0 : (L == 1) ? NOUT0 : NOUT0 + NOUT1;
    const int obase = (L == 0) ? 0 : (L == 1) ? NOUT0 + 1 : NOUT0 + NOUT1 + 2;
    const int* c  = cnt + cbase;
    int* ofs      = offs + obase;
    int* cur      = cursor + cbase;

    __shared__ int lds[1024];
    const int t = threadIdx.x;
    constexpr int CHUNK = 5;              // covers nout <= 5120
    const int base = t * CHUNK;
    int vals[CHUNK];
    int local = 0;
#pragma unroll
    for (int k = 0; k < CHUNK; ++k) {
        const int i = base + k;
        const int v = (i < nout) ? c[i] : 0;
        vals[k] = v;
        local += v;
    }
    lds[t] = local;
    __syncthreads();
    for (int d = 1; d < 1024; d <<= 1) {
        const int v = (t >= d) ? lds[t - d] : 0;
        __syncthreads();
        lds[t] += v;
        __syncthreads();
    }
    int excl = lds[t] - local;
#pragma unroll
    for (int k = 0; k < CHUNK; ++k) {
        const int i = base + k;
        if (i < nout) { ofs[i] = excl; cur[i] = excl; }
        excl += vals[k];
    }
    if (t == 1023) ofs[nout] = lds[1023];
}

__global__ __launch_bounds__(256) void scatter_edges(
    const int* __restrict__ src0, const int* __restrict__ dst0,
    const int* __restrict__ src1, const int* __restrict__ dst1,
    const int* __restrict__ src2, const int* __restrict__ dst2,
    int* __restrict__ cursor, int* __restrict__ csr)
{
    const int i = blockIdx.x * 256 + threadIdx.x;
    if (i < NE0) {
        const int pos = atomicAdd(&cursor[dst0[i]], 1);
        csr[pos] = src0[i];
    } else if (i < NE0 + NE1) {
        const int k = i - NE0;
        const int pos = atomicAdd(&cursor[NOUT0 + dst1[k]], 1);
        csr[NE0 + pos] = src1[k];
    } else if (i < NE0 + NE1 + NE2) {
        const int k = i - NE0 - NE1;
        const int pos = atomicAdd(&cursor[NOUT0 + NOUT1 + dst2[k]], 1);
        csr[NE0 + NE1 + pos] = src2[k];
    }
}

// ---------------------------------------------------------------------------
// One layer: block j sums rows xT[csr[e]] over its bucket, mean+relu, scaled
// by pnext (the NEXT layer's p, fused), written transposed.
// 2-edge unroll with dual accumulators to keep 2 float4 loads in flight.
__global__ __launch_bounds__(256) void layer_fwd(
    const float4* __restrict__ xT, const int* __restrict__ csr,
    const int* __restrict__ offs, const float* __restrict__ pnext,
    float4* __restrict__ yT)
{
    const int j = blockIdx.x;
    const int t = threadIdx.x;
    const int beg = offs[j], end = offs[j + 1];

    float4 a0 = make_float4(0.f, 0.f, 0.f, 0.f);
    float4 a1 = make_float4(0.f, 0.f, 0.f, 0.f);
    int e = beg;
    for (; e + 2 <= end; e += 2) {
        const int s0 = csr[e], s1 = csr[e + 1];
        const float4 v0 = xT[(size_t)s0 * (Bsz / 4) + t];
        const float4 v1 = xT[(size_t)s1 * (Bsz / 4) + t];
        a0.x += v0.x; a0.y += v0.y; a0.z += v0.z; a0.w += v0.w;
        a1.x += v1.x; a1.y += v1.y; a1.z += v1.z; a1.w += v1.w;
    }
    if (e < end) {
        const float4 v = xT[(size_t)csr[e] * (Bsz / 4) + t];
        a0.x += v.x; a0.y += v.y; a0.z += v.z; a0.w += v.w;
    }
    a0.x += a1.x; a0.y += a1.y; a0.z += a1.z; a0.w += a1.w;

    const float inv = 1.0f / fmaxf((float)(end - beg), 1.0f);
    const float sc = pnext ? pnext[j] : 1.0f;
    float4 r;
    r.x = fmaxf(a0.x * inv, 0.f) * sc;
    r.y = fmaxf(a0.y * inv, 0.f) * sc;
    r.z = fmaxf(a0.z * inv, 0.f) * sc;
    r.w = fmaxf(a0.w * inv, 0.f) * sc;
    yT[(size_t)j * (Bsz / 4) + t] = r;
}

// ---------------------------------------------------------------------------
// Head: out (B,10) = y2 (B,256) @ W.T (256,10) + b, with y2 stored transposed.
__global__ __launch_bounds__(256) void head_gemm(
    const float* __restrict__ y2T, const float* __restrict__ W,
    const float* __restrict__ bias, float* __restrict__ out)
{
    __shared__ float ws[10 * 256];
    __shared__ float bs[10];
    const int t = threadIdx.x;
    for (int i = t; i < 10 * 256; i += 256) ws[i] = W[i];
    if (t < 10) bs[t] = bias[t];
    __syncthreads();

    const int b = blockIdx.x * 256 + t;
    float acc[10];
#pragma unroll
    for (int o = 0; o < 10; ++o) acc[o] = bs[o];
    for (int k = 0; k < 256; ++k) {
        const float v = y2T[(size_t)k * Bsz + b];
#pragma unroll
        for (int o = 0; o < 10; ++o) acc[o] += v * ws[o * 256 + k];
    }
#pragma unroll
    for (int o = 0; o < 10; ++o) out[(size_t)b * 10 + o] = acc[o];
}

// ---------------------------------------------------------------------------
extern "C" void kernel_launch(void* const* d_in, const int* in_sizes, int n_in,
                              void* d_out, int out_size, void* d_ws, size_t ws_size,
                              hipStream_t stream)
{
    const float* data = (const float*)d_in[0];
    const float* p0   = (const float*)d_in[1];
    const float* p1   = (const float*)d_in[2];
    const float* p2   = (const float*)d_in[3];
    const float* W    = (const float*)d_in[4];
    const float* bias = (const float*)d_in[5];
    const int* src0 = (const int*)d_in[6];
    const int* dst0 = (const int*)d_in[7];
    const int* src1 = (const int*)d_in[8];
    const int* dst1 = (const int*)d_in[9];
    const int* src2 = (const int*)d_in[10];
    const int* dst2 = (const int*)d_in[11];

    char* ws = (char*)d_ws;
    auto align = [](size_t x) { return (x + 255) & ~size_t(255); };
    size_t o = 0;
    float* dataT = (float*)(ws + o); o = align(o + (size_t)F0 * Bsz * 4);
    float* y0    = (float*)(ws + o); o = align(o + (size_t)NOUT0 * Bsz * 4);
    float* y1    = (float*)(ws + o); o = align(o + (size_t)NOUT1 * Bsz * 4);
    float* y2    = (float*)(ws + o); o = align(o + (size_t)NOUT2 * Bsz * 4);
    int* cnt     = (int*)(ws + o);   o = align(o + (size_t)CNT_N * 4);
    int* offs    = (int*)(ws + o);   o = align(o + (size_t)OFFS_N * 4);
    int* cursor  = (int*)(ws + o);   o = align(o + (size_t)CNT_N * 4);
    int* csr     = (int*)(ws + o);   o = align(o + (size_t)CSR_N * 4);

    hipMemsetAsync(cnt, 0, (size_t)CNT_N * 4, stream);

    constexpr int totE = NE0 + NE1 + NE2;
    count_edges<<<(totE + 255) / 256, 256, 0, stream>>>(dst0, dst1, dst2, cnt);
    scan_offs<<<3, 1024, 0, stream>>>(cnt, offs, cursor);
    scatter_edges<<<(totE + 255) / 256, 256, 0, stream>>>(
        src0, dst0, src1, dst1, src2, dst2, cursor, csr);

    transpose_scale<<<dim3((F0 + 63) / 64, Bsz / 64), 256, 0, stream>>>(data, p0, dataT);

    layer_fwd<<<NOUT0, 256, 0, stream>>>((const float4*)dataT, csr, offs, p1, (float4*)y0);
    layer_fwd<<<NOUT1, 256, 0, stream>>>((const float4*)y0, csr + NE0, offs + NOUT0 + 1, p2, (float4*)y1);
    layer_fwd<<<NOUT2, 256, 0, stream>>>((const float4*)y1, csr + NE0 + NE1, offs + NOUT0 + NOUT1 + 2,
                                          nullptr, (float4*)y2);

    head_gemm<<<Bsz / 256, 256, 0, stream>>>(y2, W, bias, (float*)d_out);
}